// Round 13
// baseline (34.811 us; speedup 1.0000x reference)
//
#include <hip/hip_runtime.h>
#include <hip/hip_bf16.h>

// Problem constants (fixed by setup_inputs):
//   x: (64, 8192) f32   weight: (8192, 2048) f32
//   random_numbers: (4,) int (int32 or int64 storage, values in [1, 2^20))
//   y: (64, 8192) f32
#define K_FULL   8192
#define M_ROWS   64
#define N_OUT    8192
#define N_COMP   2048
#define P_MERS   2147483647

// ws layout: [0, 256KB) : xcF bf16, fragment-major:
//   xcF[(s*4 + g)*512 + lane*8 + e] = xc[g*16 + (lane&15)][s*32 + (lane>>4)*8 + e]
//   (s = k-step 0..63, g = m-group 0..3) -> every A-fragment load is 64x16B contiguous.

typedef __attribute__((ext_vector_type(8))) short bf16x8;
typedef __attribute__((ext_vector_type(4))) float f32x4;

__device__ __forceinline__ short f2bfs(float f) {
    __hip_bfloat16 h = __float2bfloat16(f);
    return *reinterpret_cast<short*>(&h);
}
__device__ __forceinline__ unsigned int pk2bf(float a, float b) {
    return (unsigned int)(unsigned short)f2bfs(a)
         | ((unsigned int)(unsigned short)f2bfs(b) << 16);
}

__device__ __forceinline__ int hash_col(int j, int rn0, int rn1, int rn2, int rn3) {
    if (rn1 == 0 && rn3 == 0) {
        // int64 storage (JAX x64 on): exact hash; Mersenne fold (2^31 === 1 mod P)
        unsigned long long xx = (unsigned long long)(unsigned int)rn0 * (unsigned int)j
                              + (unsigned long long)(unsigned int)rn2;
        unsigned long long t = (xx & (unsigned long long)P_MERS) + (xx >> 31);
        if (t >= (unsigned long long)P_MERS) t -= (unsigned long long)P_MERS;
        return (int)(t & (N_COMP - 1));
    } else {
        // int32 storage (JAX x64 off): int32 wraparound + floored mod
        unsigned int t = (unsigned int)rn0 * (unsigned int)j + (unsigned int)rn1;
        int ti = (int)t;
        int m1 = ti % P_MERS;
        if (m1 < 0) m1 += P_MERS;
        return m1 & (N_COMP - 1);
    }
}

// Fused scatter+pack: block = one m row. LDS scatter-add, then pack bf16 into
// fragment-major xcF (scattered dword writes, 4KB/block -> negligible).
__global__ __launch_bounds__(1024) void k_xc(const float* __restrict__ x,
                                             const int* __restrict__ rn,
                                             unsigned int* __restrict__ xcF) {
    __shared__ float row[N_COMP];
    const int m = blockIdx.x;
    const int tid = threadIdx.x;
    row[tid] = 0.0f;
    row[tid + 1024] = 0.0f;
    const int rn0 = rn[0], rn1 = rn[1], rn2 = rn[2], rn3 = rn[3];
    __syncthreads();

    const float* xm = x + (size_t)m * K_FULL;
#pragma unroll
    for (int it = 0; it < 2; ++it) {
        int j0 = tid * 4 + it * 4096;
        float4 v = *(const float4*)(xm + j0);
        atomicAdd(&row[hash_col(j0 + 0, rn0, rn1, rn2, rn3)], v.x);
        atomicAdd(&row[hash_col(j0 + 1, rn0, rn1, rn2, rn3)], v.y);
        atomicAdd(&row[hash_col(j0 + 2, rn0, rn1, rn2, rn3)], v.z);
        atomicAdd(&row[hash_col(j0 + 3, rn0, rn1, rn2, rn3)], v.w);
    }
    __syncthreads();

    // pack c0=2*tid, c0+1 (same s,kg; adjacent e -> one dword)
    const int c0 = 2 * tid;
    const int s  = c0 >> 5;
    const int kg = (c0 >> 3) & 3;
    const int e0 = c0 & 7;
    const int g  = m >> 4;
    const int nr = m & 15;
    xcF[(((s * 4 + g) * 64 + kg * 16 + nr) << 2) + (e0 >> 1)] =
        pk2bf(row[c0], row[c0 + 1]);
}

// MFMA GEMM v9: per-block LINEAR W consumption.
// 512 blocks x 256 thr (4 waves). Block owns 16 consecutive W rows = one
// CONTIGUOUS 128KB address range, staged front-to-back into 64KB LDS (bf16,
// XOR-swizzled rows): wave w reads rows w*4..w*4+3 as 32 x 1KB contiguous
// wave-loads, all independent -> deep HBM queue, pure sequential DRAM order.
// Then all 64 k-steps computed from LDS (B) + L2-resident fragment-major
// xcF (A). ys-reduce overlays the W tile after a barrier. 3 barriers total.
__global__ __launch_bounds__(256) void k_gemm(const float* __restrict__ W,
                                              const unsigned short* __restrict__ xcF,
                                              float* __restrict__ y) {
    __shared__ char smem[65536];                 // wt[16][4096B] then ys overlay
    const int tid  = threadIdx.x;
    const int lane = tid & 63;
    const int w    = __builtin_amdgcn_readfirstlane(tid >> 6);  // wave 0..3
    const int nr   = lane & 15;
    const int kg   = lane >> 4;
    const int n0   = blockIdx.x * 16;

    // ---- stage: wave w stages rows w*4..w*4+3, each row 8KB f32 -> 4KB bf16,
    // read in pure address order (q ascending), 1KB per wave-load.
#pragma unroll
    for (int i = 0; i < 4; ++i) {
        const int r = (w * 4 + i);
        const float* src = W + (size_t)(n0 + r) * N_COMP;
        const int swz = (r & 7) << 4;
        char* dst = smem + r * 4096;
#pragma unroll
        for (int q = 0; q < 8; ++q) {
            float4 v = *(const float4*)(src + q * 256 + lane * 4);
            uint2 p = { pk2bf(v.x, v.y), pk2bf(v.z, v.w) };
            *(uint2*)(dst + ((q * 512 + lane * 8) ^ swz)) = p;
        }
    }
    __syncthreads();

    // ---- compute: wave w covers k-quarter [w*512,(w+1)*512) = 16 steps
    f32x4 acc0 = {0.f, 0.f, 0.f, 0.f};
    f32x4 acc1 = {0.f, 0.f, 0.f, 0.f};
    f32x4 acc2 = {0.f, 0.f, 0.f, 0.f};
    f32x4 acc3 = {0.f, 0.f, 0.f, 0.f};
    const unsigned short* ab = xcF + (size_t)w * 16 * 2048 + lane * 8;
    const int bswz = (nr & 7) << 4;

#pragma unroll
    for (int sk = 0; sk < 16; ++sk) {
        bf16x8 b = *(const bf16x8*)(smem + nr * 4096
                     + ((w * 1024 + sk * 64 + kg * 16) ^ bswz));
        const unsigned short* ap = ab + (size_t)sk * 2048;
        bf16x8 a0 = *(const bf16x8*)(ap);
        bf16x8 a1 = *(const bf16x8*)(ap + 512);
        bf16x8 a2 = *(const bf16x8*)(ap + 1024);
        bf16x8 a3 = *(const bf16x8*)(ap + 1536);
        acc0 = __builtin_amdgcn_mfma_f32_16x16x32_bf16(a0, b, acc0, 0, 0, 0);
        acc1 = __builtin_amdgcn_mfma_f32_16x16x32_bf16(a1, b, acc1, 0, 0, 0);
        acc2 = __builtin_amdgcn_mfma_f32_16x16x32_bf16(a2, b, acc2, 0, 0, 0);
        acc3 = __builtin_amdgcn_mfma_f32_16x16x32_bf16(a3, b, acc3, 0, 0, 0);
    }
    __syncthreads();   // all B-reads done before LDS reuse

    // ---- epilogue: ys overlays the W tile
    float (*ys)[M_ROWS][16] = (float (*)[M_ROWS][16])smem;
    // C/D layout (m89-verified): col = lane&15, row = (lane>>4)*4 + j
#pragma unroll
    for (int j = 0; j < 4; ++j) {
        ys[w][ 0 + kg * 4 + j][nr] = acc0[j];
        ys[w][16 + kg * 4 + j][nr] = acc1[j];
        ys[w][32 + kg * 4 + j][nr] = acc2[j];
        ys[w][48 + kg * 4 + j][nr] = acc3[j];
    }
    __syncthreads();

    // reduce 4 wave-partials, direct store: 1024 outputs, 4 per thread
#pragma unroll
    for (int i = 0; i < 4; ++i) {
        int o = tid + 256 * i;
        int m = o >> 4;
        int n = o & 15;
        float s = ys[0][m][n] + ys[1][m][n] + ys[2][m][n] + ys[3][m][n];
        y[(size_t)m * N_OUT + n0 + n] = s;
    }
}

extern "C" void kernel_launch(void* const* d_in, const int* in_sizes, int n_in,
                              void* d_out, int out_size, void* d_ws, size_t ws_size,
                              hipStream_t stream) {
    const float* x = (const float*)d_in[0];
    const float* W = (const float*)d_in[1];
    const int* rn  = (const int*)d_in[2];
    float* y       = (float*)d_out;

    unsigned int* xcF = (unsigned int*)d_ws;

    k_xc<<<M_ROWS, 1024, 0, stream>>>(x, rn, xcF);
    k_gemm<<<N_OUT / 16, 256, 0, stream>>>(W, (const unsigned short*)xcF, y);
}

// Round 14
// 30.756 us; speedup vs baseline: 1.1318x; 1.1318x over previous
//
#include <hip/hip_runtime.h>
#include <hip/hip_bf16.h>

// Problem constants (fixed by setup_inputs):
//   x: (64, 8192) f32   weight: (8192, 2048) f32
//   random_numbers: (4,) int (int32 or int64 storage, values in [1, 2^20))
//   y: (64, 8192) f32
#define K_FULL   8192
#define M_ROWS   64
#define N_OUT    8192
#define N_COMP   2048
#define P_MERS   2147483647

// ws layout: [0, 256KB) : xcF bf16, fragment-major:
//   xcF[(s*4 + g)*512 + lane*8 + e] = xc[g*16 + (lane&15)][s*32 + (lane>>4)*8 + e]
//   (s = k-step 0..63, g = m-group 0..3) -> every A-fragment load is 64x16B contiguous.

typedef __attribute__((ext_vector_type(8))) short bf16x8;
typedef __attribute__((ext_vector_type(4))) float f32x4;

__device__ __forceinline__ short f2bfs(float f) {
    __hip_bfloat16 h = __float2bfloat16(f);
    return *reinterpret_cast<short*>(&h);
}
__device__ __forceinline__ unsigned int pk2bf(float a, float b) {
    return (unsigned int)(unsigned short)f2bfs(a)
         | ((unsigned int)(unsigned short)f2bfs(b) << 16);
}

// Async global->LDS DMA, 16B per lane (dest = wave-uniform base + lane*16).
#define GLL(g, l) __builtin_amdgcn_global_load_lds(                          \
    (const __attribute__((address_space(1))) unsigned int*)(g),             \
    (__attribute__((address_space(3))) unsigned int*)(l), 16, 0, 0)

__device__ __forceinline__ int hash_col(int j, int rn0, int rn1, int rn2, int rn3) {
    if (rn1 == 0 && rn3 == 0) {
        // int64 storage (JAX x64 on): exact hash; Mersenne fold (2^31 === 1 mod P)
        unsigned long long xx = (unsigned long long)(unsigned int)rn0 * (unsigned int)j
                              + (unsigned long long)(unsigned int)rn2;
        unsigned long long t = (xx & (unsigned long long)P_MERS) + (xx >> 31);
        if (t >= (unsigned long long)P_MERS) t -= (unsigned long long)P_MERS;
        return (int)(t & (N_COMP - 1));
    } else {
        // int32 storage (JAX x64 off): int32 wraparound + floored mod
        unsigned int t = (unsigned int)rn0 * (unsigned int)j + (unsigned int)rn1;
        int ti = (int)t;
        int m1 = ti % P_MERS;
        if (m1 < 0) m1 += P_MERS;
        return m1 & (N_COMP - 1);
    }
}

// Fused scatter+pack: block = one m row. LDS scatter-add, then pack bf16 into
// fragment-major xcF (scattered dword writes, 4KB/block -> negligible).
__global__ __launch_bounds__(1024) void k_xc(const float* __restrict__ x,
                                             const int* __restrict__ rn,
                                             unsigned int* __restrict__ xcF) {
    __shared__ float row[N_COMP];
    const int m = blockIdx.x;
    const int tid = threadIdx.x;
    row[tid] = 0.0f;
    row[tid + 1024] = 0.0f;
    const int rn0 = rn[0], rn1 = rn[1], rn2 = rn[2], rn3 = rn[3];
    __syncthreads();

    const float* xm = x + (size_t)m * K_FULL;
#pragma unroll
    for (int it = 0; it < 2; ++it) {
        int j0 = tid * 4 + it * 4096;
        float4 v = *(const float4*)(xm + j0);
        atomicAdd(&row[hash_col(j0 + 0, rn0, rn1, rn2, rn3)], v.x);
        atomicAdd(&row[hash_col(j0 + 1, rn0, rn1, rn2, rn3)], v.y);
        atomicAdd(&row[hash_col(j0 + 2, rn0, rn1, rn2, rn3)], v.z);
        atomicAdd(&row[hash_col(j0 + 3, rn0, rn1, rn2, rn3)], v.w);
    }
    __syncthreads();

    // pack c0=2*tid, c0+1 (same s,kg; adjacent e -> one dword)
    const int c0 = 2 * tid;
    const int s  = c0 >> 5;
    const int kg = (c0 >> 3) & 3;
    const int e0 = c0 & 7;
    const int g  = m >> 4;
    const int nr = m & 15;
    xcF[(((s * 4 + g) * 64 + kg * 16 + nr) << 2) + (e0 >> 1)] =
        pk2bf(row[c0], row[c0 + 1]);
}

// MFMA GEMM v10 = R11 skeleton + global_load_lds DMA staging of RAW f32.
// 512 blocks x 512 thr (8 waves), 8 phases x 256 k, double-buffered LDS,
// per-block phase rotation. Per phase: wave w DMAs rows 2w,2w+1 (1KB each,
// no VGPR round-trip, no store-path VALU) for the NEXT phase, computes the
// CURRENT phase from LDS: B = 8 f32 ds_read + in-register bf16 convert;
// A = contiguous 64x16B fragments from L2-resident fragment-major xcF.
// One __syncthreads per phase. LDS reduce of 8 k-slices at the end.
#define WT_ROWD 260                   // padded row stride in f32 (1040B, 16B-aligned)
#define WT_TILE (16 * WT_ROWD)

__global__ __launch_bounds__(512) void k_gemm(const float* __restrict__ W,
                                              const unsigned short* __restrict__ xcF,
                                              float* __restrict__ y) {
    __shared__ float wt[2][WT_TILE];             // 2 x 16.25 KB (raw f32 tiles)
    __shared__ float ys[8][M_ROWS][16];          // 32 KB
    const int tid  = threadIdx.x;
    const int lane = tid & 63;
    const int w    = __builtin_amdgcn_readfirstlane(tid >> 6);  // wave 0..7
    const int nr   = lane & 15;
    const int kg   = lane >> 4;
    const int n0   = blockIdx.x * 16;
    const int rot  = (blockIdx.x >> 3) & 7;
    const int r0   = 2 * w;                      // rows staged by this wave

    // global sources for this wave's two rows (per-lane 16B)
    const float* g0 = W + (size_t)(n0 + r0) * N_COMP + lane * 4;
    const float* g1 = g0 + N_COMP;
    const unsigned short* ab = xcF + (size_t)w * 2048 + lane * 8;

    f32x4 acc0 = {0.f, 0.f, 0.f, 0.f};
    f32x4 acc1 = {0.f, 0.f, 0.f, 0.f};
    f32x4 acc2 = {0.f, 0.f, 0.f, 0.f};
    f32x4 acc3 = {0.f, 0.f, 0.f, 0.f};

    // ---- prologue: DMA phase `rot` into buf 0
    GLL(g0 + rot * 256, &wt[0][r0 * WT_ROWD]);
    GLL(g1 + rot * 256, &wt[0][(r0 + 1) * WT_ROWD]);
    __syncthreads();

#pragma unroll 1
    for (int p = 0; p < 8; ++p) {
        const int b  = p & 1;
        const int pm = (p + rot) & 7;        // current memory phase
        const int pn = (p + 1 + rot) & 7;    // next memory phase
        if (p < 7) {
            // issue next-phase DMA into the other buffer (no wait)
            GLL(g0 + pn * 256, &wt[b ^ 1][r0 * WT_ROWD]);
            GLL(g1 + pn * 256, &wt[b ^ 1][(r0 + 1) * WT_ROWD]);
        }
        // A fragments for k-step s = pm*8 + w
        const unsigned short* ap = ab + (size_t)pm * 16384;
        bf16x8 a0 = *(const bf16x8*)(ap);
        bf16x8 a1 = *(const bf16x8*)(ap + 512);
        bf16x8 a2 = *(const bf16x8*)(ap + 1024);
        bf16x8 a3 = *(const bf16x8*)(ap + 1536);
        // B fragment: 8 f32 from LDS row nr, k-local = w*32 + kg*8
        const float* bp = &wt[b][nr * WT_ROWD + w * 32 + kg * 8];
        float4 f0 = *(const float4*)(bp);
        float4 f1 = *(const float4*)(bp + 4);
        bf16x8 bf;
        bf[0] = f2bfs(f0.x); bf[1] = f2bfs(f0.y);
        bf[2] = f2bfs(f0.z); bf[3] = f2bfs(f0.w);
        bf[4] = f2bfs(f1.x); bf[5] = f2bfs(f1.y);
        bf[6] = f2bfs(f1.z); bf[7] = f2bfs(f1.w);
        acc0 = __builtin_amdgcn_mfma_f32_16x16x32_bf16(a0, bf, acc0, 0, 0, 0);
        acc1 = __builtin_amdgcn_mfma_f32_16x16x32_bf16(a1, bf, acc1, 0, 0, 0);
        acc2 = __builtin_amdgcn_mfma_f32_16x16x32_bf16(a2, bf, acc2, 0, 0, 0);
        acc3 = __builtin_amdgcn_mfma_f32_16x16x32_bf16(a3, bf, acc3, 0, 0, 0);
        __syncthreads();
    }

    // C/D layout (m89-verified): col = lane&15, row = (lane>>4)*4 + j
#pragma unroll
    for (int j = 0; j < 4; ++j) {
        ys[w][ 0 + kg * 4 + j][nr] = acc0[j];
        ys[w][16 + kg * 4 + j][nr] = acc1[j];
        ys[w][32 + kg * 4 + j][nr] = acc2[j];
        ys[w][48 + kg * 4 + j][nr] = acc3[j];
    }
    __syncthreads();

    // reduce 8 k-slices, direct store: 1024 outputs, 2 per thread
#pragma unroll
    for (int i = 0; i < 2; ++i) {
        int o = tid + 512 * i;
        int m = o >> 4;
        int n = o & 15;
        float s = 0.f;
#pragma unroll
        for (int q = 0; q < 8; ++q) s += ys[q][m][n];
        y[(size_t)m * N_OUT + n0 + n] = s;
    }
}

extern "C" void kernel_launch(void* const* d_in, const int* in_sizes, int n_in,
                              void* d_out, int out_size, void* d_ws, size_t ws_size,
                              hipStream_t stream) {
    const float* x = (const float*)d_in[0];
    const float* W = (const float*)d_in[1];
    const int* rn  = (const int*)d_in[2];
    float* y       = (float*)d_out;

    unsigned int* xcF = (unsigned int*)d_ws;

    k_xc<<<M_ROWS, 1024, 0, stream>>>(x, rn, xcF);
    k_gemm<<<N_OUT / 16, 512, 0, stream>>>(W, (const unsigned short*)xcF, y);
}